// Round 4
// baseline (228.535 us; speedup 1.0000x reference)
//
#include <hip/hip_runtime.h>

// Problem constants (B=1)
constexpr int L  = 2048;
constexpr int D  = 1024;
constexpr int H  = 16;
constexpr int F  = 16;   // qk feature dim per head
constexpr int HD = 64;   // v head dim
constexpr int CHUNK = 128;
constexpr int NC = L / CHUNK;  // 16
constexpr int KK = 3072;       // concat-K for split GEMMs

typedef __bf16 bf16x8 __attribute__((ext_vector_type(8)));
typedef float  f32x4  __attribute__((ext_vector_type(4)));
typedef double f64x2  __attribute__((ext_vector_type(2)));

__device__ __forceinline__ ushort f2bf(float f) {
  uint u = __builtin_bit_cast(uint, f);
  uint r = (u + 0x7FFFu + ((u >> 16) & 1u)) >> 16;
  return (ushort)r;
}
__device__ __forceinline__ float bf2f(ushort h) {
  uint u = ((uint)h) << 16;
  return __builtin_bit_cast(float, u);
}

// ---------------------------------------------------------------------------
// Build A'_V [2048][3072] bf16 = [hs_hi | hs_hi | hs_lo] per row from hs fp32.
// ---------------------------------------------------------------------------
__global__ __launch_bounds__(256) void split_cc(
    const float* __restrict__ X, ushort* __restrict__ Ap) {
  int f = blockIdx.x * 256 + threadIdx.x;           // float4 index
  if (f >= L * D / 4) return;
  int row = f >> 8;            // 256 float4 per row
  int c   = (f & 255) * 4;
  float4 v = ((const float4*)X)[f];
  ushort4 h, l;
  h.x = f2bf(v.x); l.x = f2bf(v.x - bf2f(h.x));
  h.y = f2bf(v.y); l.y = f2bf(v.y - bf2f(h.y));
  h.z = f2bf(v.z); l.z = f2bf(v.z - bf2f(h.z));
  h.w = f2bf(v.w); l.w = f2bf(v.w - bf2f(h.w));
  size_t base = (size_t)row * KK + c;
  *(ushort4*)&Ap[base]        = h;
  *(ushort4*)&Ap[base + 1024] = h;
  *(ushort4*)&Ap[base + 2048] = l;
}

// ---------------------------------------------------------------------------
// Split+transpose weight W[k][n] fp32 -> B'[n][3072] bf16 = [Wh^T | Wl^T | Wh^T].
// Grid (32,32), 256 thr.
// ---------------------------------------------------------------------------
__global__ __launch_bounds__(256) void wsplit_cc(
    const float* __restrict__ W, ushort* __restrict__ Bp) {
  __shared__ float t[32][33];
  const int tid = threadIdx.x;
  const int lx = tid & 31, ly = tid >> 5;          // ly 0..7
  const int bn = blockIdx.x * 32, bk = blockIdx.y * 32;
  #pragma unroll
  for (int i = 0; i < 32; i += 8)
    t[ly + i][lx] = W[(size_t)(bk + ly + i) * 1024 + bn + lx];  // t[k][n]
  __syncthreads();
  #pragma unroll
  for (int i = 0; i < 32; i += 8) {
    float v = t[lx][ly + i];                        // k=bk+lx, n=bn+ly+i
    ushort hh = f2bf(v);
    ushort ll = f2bf(v - bf2f(hh));
    size_t base = (size_t)(bn + ly + i) * KK + bk + lx;
    Bp[base]        = hh;
    Bp[base + 1024] = ll;
    Bp[base + 2048] = hh;
  }
}

// ---------------------------------------------------------------------------
// Concat-K bf16 GEMM: C[2048][N] fp32 = A'[2048][3072] @ B'[N][3072]^T.
// BM=64, BN=128, BK=64, 256 thr = 4 waves (2x2), wave-tile 32x64 (2x4 frags
// of 16x16, mfma_f32_16x16x32_bf16). Double-buffered LDS, reg-staged with
// issue-early/write-late. LDS rows padded to 144 B.
// ---------------------------------------------------------------------------
__global__ __launch_bounds__(256) void gemm_cc_bf16(
    const ushort* __restrict__ Ap, const ushort* __restrict__ Bp,
    float* __restrict__ C, int N) {
  constexpr int NSTEP = KK / 64;   // 48
  constexpr int LDT = 72;          // bf16 per LDS row (144 B)
  __shared__ __bf16 As[2][64][LDT];
  __shared__ __bf16 Bs[2][128][LDT];
  const int tid  = threadIdx.x;
  const int wave = tid >> 6, lane = tid & 63;
  const int wm = (wave >> 1) * 32;     // 0/32
  const int wn = (wave & 1) * 64;      // 0/64
  const int brow = blockIdx.y * 64, bcol = blockIdx.x * 128;
  const int fr = lane & 15, kg = (lane >> 4) * 8;
  const int sr = tid >> 3, sc = (tid & 7) * 8;   // staging: row tid>>3 (+i*32), col

  f32x4 acc[2][4];
  #pragma unroll
  for (int fm = 0; fm < 2; ++fm)
    #pragma unroll
    for (int fn = 0; fn < 4; ++fn)
      #pragma unroll
      for (int r = 0; r < 4; ++r) acc[fm][fn][r] = 0.f;

  bf16x8 ra[2], rb[4];
  auto LOADT = [&](int t) {
    const int k0 = t * 64;
    #pragma unroll
    for (int i = 0; i < 2; ++i)
      ra[i] = *(const bf16x8*)&Ap[(size_t)(brow + i * 32 + sr) * KK + k0 + sc];
    #pragma unroll
    for (int i = 0; i < 4; ++i)
      rb[i] = *(const bf16x8*)&Bp[(size_t)(bcol + i * 32 + sr) * KK + k0 + sc];
  };
  auto WRITET = [&](int buf) {
    #pragma unroll
    for (int i = 0; i < 2; ++i) *(bf16x8*)&As[buf][i * 32 + sr][sc] = ra[i];
    #pragma unroll
    for (int i = 0; i < 4; ++i) *(bf16x8*)&Bs[buf][i * 32 + sr][sc] = rb[i];
  };

  LOADT(0); WRITET(0);
  __syncthreads();
  int cur = 0;
  for (int t = 0; t < NSTEP; ++t) {
    if (t + 1 < NSTEP) LOADT(t + 1);              // issue early (hides HBM/L2)
    bf16x8 af[2][2], bfr[4][2];
    #pragma unroll
    for (int fm = 0; fm < 2; ++fm)
      #pragma unroll
      for (int s = 0; s < 2; ++s)
        af[fm][s] = *(const bf16x8*)&As[cur][wm + fm * 16 + fr][s * 32 + kg];
    #pragma unroll
    for (int fn = 0; fn < 4; ++fn)
      #pragma unroll
      for (int s = 0; s < 2; ++s)
        bfr[fn][s] = *(const bf16x8*)&Bs[cur][wn + fn * 16 + fr][s * 32 + kg];
    #pragma unroll
    for (int s = 0; s < 2; ++s)
      #pragma unroll
      for (int fm = 0; fm < 2; ++fm)
        #pragma unroll
        for (int fn = 0; fn < 4; ++fn)
          acc[fm][fn] = __builtin_amdgcn_mfma_f32_16x16x32_bf16(
              af[fm][s], bfr[fn][s], acc[fm][fn], 0, 0, 0);
    if (t + 1 < NSTEP) WRITET(cur ^ 1);           // write late (other buffer)
    __syncthreads();
    cur ^= 1;
  }
  const int orow = (lane >> 4) * 4;
  #pragma unroll
  for (int fm = 0; fm < 2; ++fm)
    #pragma unroll
    for (int fn = 0; fn < 4; ++fn)
      #pragma unroll
      for (int r = 0; r < 4; ++r)
        C[(size_t)(brow + wm + fm * 16 + orow + r) * N + bcol + wn + fn * 16 + fr] =
            acc[fm][fn][r];
}

// ---------------------------------------------------------------------------
// Q/K projection, scalar fp64 accumulation (proven-correct structure), v3:
// 64x64 tile, 256 thr, micro 4x4, grid (8,32)=256 blocks (1/CU).
// B tile stored [n][k] (LDB=17 doubles) -> inner B reads conflict-free
// (banks 2*tx+{0,1}); A reads are 4-address broadcasts. Double-buffered LDS,
// reg-staged issue-early/write-late. Cols [0,256)->Q via Wq; else K via Wk.
// ---------------------------------------------------------------------------
__global__ __launch_bounds__(256) void gemm_qk_f64_v3(
    const float* __restrict__ hs, const float* __restrict__ Wq, const float* __restrict__ Wk,
    float* __restrict__ Qo, float* __restrict__ Ko) {
  constexpr int LDA = 68;  // doubles per A k-row ([k][m], 64 used; 544B, 16B-aligned)
  constexpr int LDB = 17;  // doubles per B n-row ([n][k], 16 used; 136B)
  __shared__ double Asd[2][16][LDA];
  __shared__ double Bsd[2][64][LDB];
  const int tid = threadIdx.x;
  const int tx = tid & 15;         // col base: tx + 16*c
  const int ty = tid >> 4;         // rows ty*4 .. ty*4+3
  const int brow = blockIdx.y * 64;
  const int bcol = blockIdx.x * 64;        // 0..448
  const float* W = (bcol < 256) ? Wq : Wk;
  float* Out     = (bcol < 256) ? Qo : Ko;
  const int wcol = bcol & 255;

  const int am = tid >> 2, ak = (tid & 3) * 4;     // A staging: row am, k ak..+3
  const int bk = tid >> 4, bn = (tid & 15) * 4;    // B staging: k bk, cols bn..+3

  double acc[4][4] = {};

  float4 ra, rb;
  auto LOADT = [&](int k0) {
    ra = *(const float4*)&hs[(size_t)(brow + am) * D + k0 + ak];
    rb = *(const float4*)&W[(size_t)(k0 + bk) * 256 + wcol + bn];
  };
  auto WRITET = [&](int buf) {
    Asd[buf][ak + 0][am] = (double)ra.x; Asd[buf][ak + 1][am] = (double)ra.y;
    Asd[buf][ak + 2][am] = (double)ra.z; Asd[buf][ak + 3][am] = (double)ra.w;
    Bsd[buf][bn + 0][bk] = (double)rb.x; Bsd[buf][bn + 1][bk] = (double)rb.y;
    Bsd[buf][bn + 2][bk] = (double)rb.z; Bsd[buf][bn + 3][bk] = (double)rb.w;
  };

  LOADT(0); WRITET(0);
  __syncthreads();
  int cur = 0;
  for (int t = 0; t < D / 16; ++t) {
    if (t + 1 < D / 16) LOADT((t + 1) * 16);       // issue early
    #pragma unroll
    for (int k = 0; k < 16; ++k) {
      double a[4], b[4];
      *(f64x2*)&a[0] = *(const f64x2*)&Asd[cur][k][ty * 4];
      *(f64x2*)&a[2] = *(const f64x2*)&Asd[cur][k][ty * 4 + 2];
      #pragma unroll
      for (int c = 0; c < 4; ++c) b[c] = Bsd[cur][tx + 16 * c][k];
      #pragma unroll
      for (int r = 0; r < 4; ++r)
        #pragma unroll
        for (int c = 0; c < 4; ++c)
          acc[r][c] = fma(a[r], b[c], acc[r][c]);
    }
    if (t + 1 < D / 16) WRITET(cur ^ 1);           // write late (other buffer)
    __syncthreads();
    cur ^= 1;
  }
  #pragma unroll
  for (int r = 0; r < 4; ++r)
    #pragma unroll
    for (int c = 0; c < 4; ++c)
      Out[(size_t)(brow + ty * 4 + r) * 256 + wcol + tx + 16 * c] = (float)acc[r][c];
}

// ---------------------------------------------------------------------------
// Per-chunk state sums: S[h][c][f][e] = sum_{m in chunk} k[m,h,f]*v[m,h,e];
// KS[h][c][f] = sum_m k[m,h,f] (fp64). Grid (NC, H), 256 threads.
// ---------------------------------------------------------------------------
__global__ __launch_bounds__(256) void chunk_state(
    const float* __restrict__ Kq, const float* __restrict__ V,
    float* __restrict__ S, double* __restrict__ KS) {
  const int c = blockIdx.x, h = blockIdx.y;
  __shared__ float Ks[CHUNK][F];
  __shared__ float Vs[CHUNK][HD];
  const int tid = threadIdx.x;
  #pragma unroll
  for (int i = 0; i < 2; ++i) {
    int g = i * 256 + tid;
    int m = g >> 2, f0 = (g & 3) * 4;
    *(float4*)&Ks[m][f0] = *(const float4*)&Kq[(size_t)(c * CHUNK + m) * (H * F) + h * F + f0];
  }
  #pragma unroll
  for (int i = 0; i < 8; ++i) {
    int g = i * 256 + tid;
    int m = g >> 4, e0 = (g & 15) * 4;
    *(float4*)&Vs[m][e0] = *(const float4*)&V[(size_t)(c * CHUNK + m) * (H * HD) + h * HD + e0];
  }
  __syncthreads();
  const int f = tid >> 4, e0 = (tid & 15) * 4;
  float4 acc = make_float4(0.f, 0.f, 0.f, 0.f);
  for (int m = 0; m < CHUNK; ++m) {
    float kv = Ks[m][f];
    float4 v4 = *(const float4*)&Vs[m][e0];
    acc.x = fmaf(kv, v4.x, acc.x);
    acc.y = fmaf(kv, v4.y, acc.y);
    acc.z = fmaf(kv, v4.z, acc.z);
    acc.w = fmaf(kv, v4.w, acc.w);
  }
  *(float4*)&S[((((size_t)h * NC) + c) * F + f) * HD + e0] = acc;
  if (tid < F) {
    double s = 0.0;
    for (int m = 0; m < CHUNK; ++m) s += (double)Ks[m][tid];
    KS[(((size_t)h * NC) + c) * F + tid] = s;
  }
}

// ---------------------------------------------------------------------------
// In-place exclusive prefix over chunks for S (fp32) and KS (fp64). Grid H.
// ---------------------------------------------------------------------------
__global__ void prefix_state(float* __restrict__ S, double* __restrict__ KS) {
  const int h = blockIdx.x;
  const int tid = threadIdx.x;
  float run = 0.f;
  for (int c = 0; c < NC; ++c) {
    size_t idx = (((size_t)h * NC) + c) * (F * HD) + tid;
    float v = S[idx];
    S[idx] = run;
    run += v;
  }
  if (tid < F) {
    double rk = 0.0;
    for (int c = 0; c < NC; ++c) {
      size_t idx = (((size_t)h * NC) + c) * F + tid;
      double v = KS[idx];
      KS[idx] = rk;
      rk += v;
    }
  }
}

// ---------------------------------------------------------------------------
// Fused chunk attention; writes Ys directly into A' concat layout
// ([Ys_hi | Ys_hi | Ys_lo] per row of 3072). Grid (NC, H), 256 threads.
// ---------------------------------------------------------------------------
__global__ __launch_bounds__(256) void attn_chunk(
    const float* __restrict__ Q, const float* __restrict__ Kq, const float* __restrict__ V,
    const float* __restrict__ Sin, const double* __restrict__ kcum,
    ushort* __restrict__ Ay) {
  const int c = blockIdx.x, h = blockIdx.y;
  __shared__ float Ks[CHUNK][F];
  __shared__ float Vs[CHUNK][HD];
  __shared__ float Ss[F][HD];
  __shared__ double kcs[F];
  __shared__ float zs[CHUNK];
  const int tid = threadIdx.x;

  #pragma unroll
  for (int i = 0; i < 2; ++i) {
    int g = i * 256 + tid;
    int m = g >> 2, f0 = (g & 3) * 4;
    *(float4*)&Ks[m][f0] = *(const float4*)&Kq[(size_t)(c * CHUNK + m) * (H * F) + h * F + f0];
  }
  #pragma unroll
  for (int i = 0; i < 8; ++i) {
    int g = i * 256 + tid;
    int m = g >> 4, e0 = (g & 15) * 4;
    *(float4*)&Vs[m][e0] = *(const float4*)&V[(size_t)(c * CHUNK + m) * (H * HD) + h * HD + e0];
  }
  {
    int f = tid >> 4, e0 = (tid & 15) * 4;
    *(float4*)&Ss[f][e0] = *(const float4*)&Sin[(((size_t)h * NC) + c) * (F * HD) + f * HD + e0];
  }
  if (tid < F) kcs[tid] = kcum[(((size_t)h * NC) + c) * F + tid];
  __syncthreads();

  const int rg = tid >> 3;
  const int cg = tid & 7;
  const int i0 = rg * 4;
  const int e0 = cg * 8;

  float q[4][F];
  #pragma unroll
  for (int r = 0; r < 4; ++r)
    #pragma unroll
    for (int f0 = 0; f0 < F; f0 += 4)
      *(float4*)&q[r][f0] = *(const float4*)&Q[(size_t)(c * CHUNK + i0 + r) * (H * F) + h * F + f0];

  float acc[4][8];
  #pragma unroll
  for (int r = 0; r < 4; ++r)
    #pragma unroll
    for (int j = 0; j < 8; ++j) acc[r][j] = 0.f;
  float den[4] = {0.f, 0.f, 0.f, 0.f};

  const int mmax = ((tid >> 6) + 1) * 32;
  for (int m = 0; m < mmax; ++m) {
    float kr[F];
    #pragma unroll
    for (int f0 = 0; f0 < F; f0 += 4)
      *(float4*)&kr[f0] = *(const float4*)&Ks[m][f0];
    float a[4];
    #pragma unroll
    for (int r = 0; r < 4; ++r) {
      float s = 0.f;
      #pragma unroll
      for (int f = 0; f < F; ++f) s = fmaf(q[r][f], kr[f], s);
      a[r] = (m <= i0 + r) ? s : 0.f;
      den[r] += a[r];
    }
    float v8[8];
    *(float4*)&v8[0] = *(const float4*)&Vs[m][e0];
    *(float4*)&v8[4] = *(const float4*)&Vs[m][e0 + 4];
    #pragma unroll
    for (int r = 0; r < 4; ++r)
      #pragma unroll
      for (int j = 0; j < 8; ++j)
        acc[r][j] = fmaf(a[r], v8[j], acc[r][j]);
  }

  #pragma unroll
  for (int f = 0; f < F; ++f) {
    float s8[8];
    *(float4*)&s8[0] = *(const float4*)&Ss[f][e0];
    *(float4*)&s8[4] = *(const float4*)&Ss[f][e0 + 4];
    #pragma unroll
    for (int r = 0; r < 4; ++r)
      #pragma unroll
      for (int j = 0; j < 8; ++j)
        acc[r][j] = fmaf(q[r][f], s8[j], acc[r][j]);
  }

  if (cg == 0) {
    #pragma unroll
    for (int r = 0; r < 4; ++r) {
      double dd = (double)den[r];
      #pragma unroll
      for (int f = 0; f < F; ++f) dd += (double)q[r][f] * kcs[f];
      zs[i0 + r] = (float)(1.0 / (dd + 1e-12));
    }
  }
  __syncthreads();

  #pragma unroll
  for (int r = 0; r < 4; ++r) {
    float zz = zs[i0 + r];
    ushort4 h4a, h4b, l4a, l4b;
    float o;
    o = acc[r][0] * zz; h4a.x = f2bf(o); l4a.x = f2bf(o - bf2f(h4a.x));
    o = acc[r][1] * zz; h4a.y = f2bf(o); l4a.y = f2bf(o - bf2f(h4a.y));
    o = acc[r][2] * zz; h4a.z = f2bf(o); l4a.z = f2bf(o - bf2f(h4a.z));
    o = acc[r][3] * zz; h4a.w = f2bf(o); l4a.w = f2bf(o - bf2f(h4a.w));
    o = acc[r][4] * zz; h4b.x = f2bf(o); l4b.x = f2bf(o - bf2f(h4b.x));
    o = acc[r][5] * zz; h4b.y = f2bf(o); l4b.y = f2bf(o - bf2f(h4b.y));
    o = acc[r][6] * zz; h4b.z = f2bf(o); l4b.z = f2bf(o - bf2f(h4b.z));
    o = acc[r][7] * zz; h4b.w = f2bf(o); l4b.w = f2bf(o - bf2f(h4b.w));
    size_t base = (size_t)(c * CHUNK + i0 + r) * KK + h * HD + e0;
    *(ushort4*)&Ay[base]            = h4a;
    *(ushort4*)&Ay[base + 4]        = h4b;
    *(ushort4*)&Ay[base + 1024]     = h4a;
    *(ushort4*)&Ay[base + 1028]     = h4b;
    *(ushort4*)&Ay[base + 2048]     = l4a;
    *(ushort4*)&Ay[base + 2052]     = l4b;
  }
}

// ---------------------------------------------------------------------------
extern "C" void kernel_launch(void* const* d_in, const int* in_sizes, int n_in,
                              void* d_out, int out_size, void* d_ws, size_t ws_size,
                              hipStream_t stream) {
  const float* hs = (const float*)d_in[0];
  const float* Wq = (const float*)d_in[1];
  const float* Wk = (const float*)d_in[2];
  const float* Wv = (const float*)d_in[3];
  const float* Wo = (const float*)d_in[4];
  float* out = (float*)d_out;

  char* ws = (char*)d_ws;
  const size_t MB = 1 << 20;
  ushort* Ap  = (ushort*)(ws + 0 * MB);    // 12 MB [2048][3072] bf16 (A'_V, then Ys')
  ushort* Bp  = (ushort*)(ws + 12 * MB);   //  6 MB [1024][3072] bf16 (B'_V, then B'_O)
  float*  Vb  = (float*)(ws + 18 * MB);    //  8 MB [2048][1024] fp32
  float*  Qb  = (float*)(ws + 26 * MB);    //  2 MB [2048][256]
  float*  Kb  = (float*)(ws + 28 * MB);    //  2 MB
  float*  S   = (float*)(ws + 30 * MB);    //  1 MB [H][NC][F][HD] (Sc -> Sin in place)
  // KS lives in d_out (8 MB): used as scratch in steps 5-8, fully overwritten
  // by step 9's GEMM. Keeps workspace peak at exactly 31 MB.
  double* KS  = (double*)d_out;            // 32 KB [H][NC][F] (ksum -> kcum in place)

  // 1) A'_V = [hs_hi | hs_hi | hs_lo]
  split_cc<<<dim3(L * D / 4 / 256), 256, 0, stream>>>(hs, Ap);
  // 2) B'_V = [WvT_hi | WvT_lo | WvT_hi]
  wsplit_cc<<<dim3(32, 32), 256, 0, stream>>>(Wv, Bp);
  // 3) Q,K projection (scalar fp64 accumulate -> fp32 store)
  gemm_qk_f64_v3<<<dim3(8, 32), 256, 0, stream>>>(hs, Wq, Wk, Qb, Kb);
  // 4) V projection (single concat-K bf16 GEMM)
  gemm_cc_bf16<<<dim3(1024 / 128, 2048 / 64), 256, 0, stream>>>(Ap, Bp, Vb, 1024);
  // 5) per-chunk k^T v states + fp64 k sums
  chunk_state<<<dim3(NC, H), 256, 0, stream>>>(Kb, Vb, S, KS);
  // 6) in-place exclusive prefix over chunks
  prefix_state<<<H, 1024, 0, stream>>>(S, KS);
  // 7) B'_O = [WoT_hi | WoT_lo | WoT_hi] (B'_V dead after step 4)
  wsplit_cc<<<dim3(32, 32), 256, 0, stream>>>(Wo, Bp);
  // 8) fused chunk attention -> Ys' concat layout (overwrites A')
  attn_chunk<<<dim3(NC, H), 256, 0, stream>>>(Qb, Kb, Vb, S, KS, Ap);
  // 9) output projection (fully overwrites d_out, retiring the KS scratch)
  gemm_cc_bf16<<<dim3(1024 / 128, 2048 / 64), 256, 0, stream>>>(Ap, Bp, out, 1024);
}